// Round 1
// baseline (627.034 us; speedup 1.0000x reference)
//
#include <hip/hip_runtime.h>
#include <hip/hip_bf16.h>

typedef __attribute__((ext_vector_type(8))) short bf16x8;
typedef __attribute__((ext_vector_type(4))) float f32x4;

#define MFMA(a, b, c) __builtin_amdgcn_mfma_f32_16x16x32_bf16(a, b, c, 0, 0, 0)

__device__ __forceinline__ unsigned int pack2(float x, float y) {
  union { float f; unsigned u; } a{x}, b{y};
  unsigned ax = a.u + 0x7FFFu + ((a.u >> 16) & 1u);
  unsigned bx = b.u + 0x7FFFu + ((b.u >> 16) & 1u);
  return (ax >> 16) | (bx & 0xFFFF0000u);
}
__device__ __forceinline__ unsigned short f2bf(float x) {
  union { float f; unsigned u; } a{x};
  unsigned r = a.u + 0x7FFFu + ((a.u >> 16) & 1u);
  return (unsigned short)(r >> 16);
}

// token t (shifted-window order) -> flat pixel base offset (elements) in x / y
__device__ __forceinline__ int src_off(int t) {
  int wi = t >> 6, n = t & 63;
  int b = wi >> 10, wr = (wi >> 5) & 31, wc = wi & 31;
  int hh = (wr * 8 + (n >> 3) + 4) & 255;
  int ww = (wc * 8 + (n & 7) + 4) & 255;
  return ((((b << 8) | hh) << 8) | ww) << 8;
}

// ---------------- prep: weight transposes + relative-position bias ----------
__global__ __launch_bounds__(256) void prep_kernel(
    const float* __restrict__ w_qkv, const float* __restrict__ w_proj,
    const float* __restrict__ bias_table,
    unsigned short* __restrict__ wqkvt, unsigned short* __restrict__ wpt,
    float* __restrict__ rb) {
  int i = blockIdx.x * 256 + threadIdx.x;
  if (i < 196608) {                       // wqkvt[n][k] = w_qkv[k][n], bf16
    int n = i >> 8, k = i & 255;
    wqkvt[i] = f2bf(w_qkv[k * 768 + n]);
  } else if (i < 262144) {                // wpt[n][k] = w_proj[k][n], bf16
    int j = i - 196608;
    int n = j >> 8, k = j & 255;
    wpt[j] = f2bf(w_proj[k * 256 + n]);
  } else {                                // rb[h][n][m]
    int j = i - 262144;
    int h = j >> 12, n = (j >> 6) & 63, m = j & 63;
    int idx = ((n >> 3) - (m >> 3) + 7) * 15 + ((n & 7) - (m & 7) + 7);
    rb[j] = bias_table[idx * 8 + h];
  }
}

// ---------------- QKV GEMM: [262144,256] @ [256,768], 128x128 tile, BK=64 ---
__global__ __launch_bounds__(256) void qkv_gemm_kernel(
    const float* __restrict__ x, const float* __restrict__ b_qkv,
    const unsigned short* __restrict__ wqkvt,
    unsigned short* __restrict__ qws, unsigned short* __restrict__ kws,
    unsigned short* __restrict__ vws) {
  __shared__ unsigned short Alds[128 * 64];
  __shared__ unsigned short Blds[128 * 64];
  // XCD-chunked swizzle: the 6 N-blocks of one M-panel land on the same XCD.
  int wk = (blockIdx.x & 7) * 1536 + (blockIdx.x >> 3);
  int mblk = wk / 6, nblk = wk - mblk * 6;
  int m0 = mblk * 128, n0 = nblk * 128;
  int tid = threadIdx.x;
  int lane = tid & 63, w = tid >> 6;
  int ln = lane & 15, g = lane >> 4;
  int wm = w >> 1, wn = w & 1;

  f32x4 acc[4][4] = {};
  for (int kt = 0; kt < 4; ++kt) {
    int k0 = kt * 64;
    // stage A (fp32 gather + cvt) and B (bf16) — lane-sequential LDS chunks
#pragma unroll
    for (int c = 0; c < 4; ++c) {
      int ch = tid + 256 * c;             // 1024 chunks of 8 elems
      int row = ch >> 3, kcol = (ch & 7) * 8;
      const float4* s4 = (const float4*)(x + src_off(m0 + row) + k0 + kcol);
      float4 fa = s4[0], fb = s4[1];
      uint4 wv;
      wv.x = pack2(fa.x, fa.y); wv.y = pack2(fa.z, fa.w);
      wv.z = pack2(fb.x, fb.y); wv.w = pack2(fb.z, fb.w);
      *(uint4*)&Alds[ch * 8] = wv;
      const uint4* bs = (const uint4*)(wqkvt + (n0 + row) * 256 + k0 + kcol);
      *(uint4*)&Blds[ch * 8] = bs[0];
    }
    __syncthreads();
#pragma unroll
    for (int sub = 0; sub < 2; ++sub) {
      bf16x8 af[4], bfr[4];
#pragma unroll
      for (int mt = 0; mt < 4; ++mt)
        af[mt] = *(const bf16x8*)&Alds[(64 * wm + 16 * mt + ln) * 64 + sub * 32 + 8 * g];
#pragma unroll
      for (int nt = 0; nt < 4; ++nt)
        bfr[nt] = *(const bf16x8*)&Blds[(64 * wn + 16 * nt + ln) * 64 + sub * 32 + 8 * g];
#pragma unroll
      for (int mt = 0; mt < 4; ++mt)
#pragma unroll
        for (int nt = 0; nt < 4; ++nt)
          acc[mt][nt] = MFMA(af[mt], bfr[nt], acc[mt][nt]);
    }
    __syncthreads();
  }
  // epilogue: scatter into Q (scaled) / K ([win][h][n][d]) / V-transposed ([win][h][d][n])
  int sec = n0 >> 8;                      // 0=Q 1=K 2=V (BN=128 divides 256)
  int jbase = (n0 & 255) + 64 * wn;
#pragma unroll
  for (int mt = 0; mt < 4; ++mt) {
#pragma unroll
    for (int nt = 0; nt < 4; ++nt) {
      int jq = jbase + 16 * nt + ln;      // col within the 256-wide section
      int h = jq >> 5, d = jq & 31;
      float bias = b_qkv[sec * 256 + jq];
#pragma unroll
      for (int jr = 0; jr < 4; ++jr) {
        int t = m0 + 64 * wm + 16 * mt + 4 * g + jr;
        int wi = t >> 6, n = t & 63;
        float v = acc[mt][nt][jr] + bias;
        if (sec == 0) {
          qws[((wi * 8 + h) * 64 + n) * 32 + d] = f2bf(v * 0.17677669529663687f);
        } else if (sec == 1) {
          kws[((wi * 8 + h) * 64 + n) * 32 + d] = f2bf(v);
        } else {
          vws[((wi * 8 + h) * 32 + d) * 64 + n] = f2bf(v);
        }
      }
    }
  }
}

// ---------------- attention + output projection, 1 block / window -----------
__global__ __launch_bounds__(512) void attn_proj_kernel(
    const unsigned short* __restrict__ qws, const unsigned short* __restrict__ kws,
    const unsigned short* __restrict__ vws, const unsigned short* __restrict__ wpt,
    const float* __restrict__ rb, const float* __restrict__ b_proj,
    float* __restrict__ y) {
  __shared__ unsigned short sm[20480];    // per-wave P scratch (8x2560) / AO (64x264) union
  int wi = blockIdx.x;
  int tid = threadIdx.x;
  int h = tid >> 6, lane = tid & 63;
  int ln = lane & 15, g = lane >> 4;
  const unsigned short* qb = qws + (wi * 8 + h) * 2048;
  const unsigned short* kb = kws + (wi * 8 + h) * 2048;
  const unsigned short* vb = vws + (wi * 8 + h) * 2048;

  bf16x8 qf[4], kf[4];
#pragma unroll
  for (int mt = 0; mt < 4; ++mt) qf[mt] = *(const bf16x8*)(qb + (16 * mt + ln) * 32 + 8 * g);
#pragma unroll
  for (int nt = 0; nt < 4; ++nt) kf[nt] = *(const bf16x8*)(kb + (16 * nt + ln) * 32 + 8 * g);

  // scores = rel_bias + Q·K^T   (acc preloaded with bias)
  f32x4 s[4][4];
  const float* rbh = rb + h * 4096;
#pragma unroll
  for (int mt = 0; mt < 4; ++mt)
#pragma unroll
    for (int nt = 0; nt < 4; ++nt)
#pragma unroll
      for (int jr = 0; jr < 4; ++jr)
        s[mt][nt][jr] = rbh[(16 * mt + 4 * g + jr) * 64 + 16 * nt + ln];
#pragma unroll
  for (int mt = 0; mt < 4; ++mt)
#pragma unroll
    for (int nt = 0; nt < 4; ++nt)
      s[mt][nt] = MFMA(qf[mt], kf[nt], s[mt][nt]);

  // wave-parallel softmax: each row lives in one 16-lane group (4 vals/lane)
#pragma unroll
  for (int mt = 0; mt < 4; ++mt) {
#pragma unroll
    for (int jr = 0; jr < 4; ++jr) {
      float mx = fmaxf(fmaxf(s[mt][0][jr], s[mt][1][jr]), fmaxf(s[mt][2][jr], s[mt][3][jr]));
      mx = fmaxf(mx, __shfl_xor(mx, 1));
      mx = fmaxf(mx, __shfl_xor(mx, 2));
      mx = fmaxf(mx, __shfl_xor(mx, 4));
      mx = fmaxf(mx, __shfl_xor(mx, 8));
      float sum = 0.f;
#pragma unroll
      for (int nt = 0; nt < 4; ++nt) {
        float p = __expf(s[mt][nt][jr] - mx);
        s[mt][nt][jr] = p; sum += p;
      }
      sum += __shfl_xor(sum, 1);
      sum += __shfl_xor(sum, 2);
      sum += __shfl_xor(sum, 4);
      sum += __shfl_xor(sum, 8);
      float inv = 1.f / sum;
#pragma unroll
      for (int nt = 0; nt < 4; ++nt) s[mt][nt][jr] *= inv;
    }
  }

  // PV: P chunk -> per-wave LDS scratch (pitch 40), V^T frags straight from ws
  unsigned short* sc = sm + h * 2560;
  f32x4 o[4][2] = {};
#pragma unroll
  for (int kk = 0; kk < 2; ++kk) {
#pragma unroll
    for (int mt = 0; mt < 4; ++mt)
#pragma unroll
      for (int q = 0; q < 2; ++q)
#pragma unroll
        for (int jr = 0; jr < 4; ++jr)
          sc[(16 * mt + 4 * g + jr) * 40 + q * 16 + ln] = f2bf(s[mt][2 * kk + q][jr]);
    bf16x8 vf[2];
#pragma unroll
    for (int nd = 0; nd < 2; ++nd)
      vf[nd] = *(const bf16x8*)(vb + (16 * nd + ln) * 64 + 32 * kk + 8 * g);
#pragma unroll
    for (int mt = 0; mt < 4; ++mt) {
      bf16x8 pa = *(const bf16x8*)&sc[(16 * mt + ln) * 40 + 8 * g];
      o[mt][0] = MFMA(pa, vf[0], o[mt][0]);
      o[mt][1] = MFMA(pa, vf[1], o[mt][1]);
    }
  }
  __syncthreads();                        // scratch region is about to become AO
  // AO[64][264] bf16: all heads' outputs
#pragma unroll
  for (int mt = 0; mt < 4; ++mt)
#pragma unroll
    for (int nd = 0; nd < 2; ++nd)
#pragma unroll
      for (int jr = 0; jr < 4; ++jr)
        sm[(16 * mt + 4 * g + jr) * 264 + h * 32 + 16 * nd + ln] = f2bf(o[mt][nd][jr]);
  __syncthreads();

  // proj: wave h computes y cols [32h, 32h+32), K=256 from AO
  f32x4 a2[4][2] = {};
#pragma unroll
  for (int ks = 0; ks < 8; ++ks) {
    bf16x8 af[4], bfr[2];
#pragma unroll
    for (int mt = 0; mt < 4; ++mt)
      af[mt] = *(const bf16x8*)&sm[(16 * mt + ln) * 264 + ks * 32 + 8 * g];
#pragma unroll
    for (int nt = 0; nt < 2; ++nt)
      bfr[nt] = *(const bf16x8*)(wpt + (32 * h + 16 * nt + ln) * 256 + ks * 32 + 8 * g);
#pragma unroll
    for (int mt = 0; mt < 4; ++mt) {
      a2[mt][0] = MFMA(af[mt], bfr[0], a2[mt][0]);
      a2[mt][1] = MFMA(af[mt], bfr[1], a2[mt][1]);
    }
  }
  // epilogue: un-shift scatter + proj bias (same index map as the gather)
  int b = wi >> 10, wr = (wi >> 5) & 31, wc = wi & 31;
#pragma unroll
  for (int mt = 0; mt < 4; ++mt)
#pragma unroll
    for (int jr = 0; jr < 4; ++jr) {
      int n = 16 * mt + 4 * g + jr;
      int hh = (wr * 8 + (n >> 3) + 4) & 255;
      int ww = (wc * 8 + (n & 7) + 4) & 255;
      int off = ((((b << 8) | hh) << 8) | ww) << 8;
#pragma unroll
      for (int nt = 0; nt < 2; ++nt) {
        int col = 32 * h + 16 * nt + ln;
        y[off + col] = a2[mt][nt][jr] + b_proj[col];
      }
    }
}

extern "C" void kernel_launch(void* const* d_in, const int* in_sizes, int n_in,
                              void* d_out, int out_size, void* d_ws, size_t ws_size,
                              hipStream_t stream) {
  const float* x          = (const float*)d_in[0];
  const float* w_qkv      = (const float*)d_in[1];
  const float* b_qkv      = (const float*)d_in[2];
  const float* w_proj     = (const float*)d_in[3];
  const float* b_proj     = (const float*)d_in[4];
  const float* bias_table = (const float*)d_in[5];
  char* ws = (char*)d_ws;
  // ws layout (bytes): Q 128MiB | K 128MiB | Vt 128MiB | wqkvt 384KiB | wpt 128KiB | rb 128KiB
  unsigned short* qws   = (unsigned short*)(ws);
  unsigned short* kws   = (unsigned short*)(ws + 134217728);
  unsigned short* vws   = (unsigned short*)(ws + 268435456);
  unsigned short* wqkvt = (unsigned short*)(ws + 402653184);
  unsigned short* wpt   = (unsigned short*)(ws + 402653184 + 393216);
  float* rb             = (float*)(ws + 402653184 + 393216 + 131072);
  float* y = (float*)d_out;

  prep_kernel<<<1152, 256, 0, stream>>>(w_qkv, w_proj, bias_table, wqkvt, wpt, rb);
  qkv_gemm_kernel<<<12288, 256, 0, stream>>>(x, b_qkv, wqkvt, qws, kws, vws);
  attn_proj_kernel<<<4096, 512, 0, stream>>>(qws, kws, vws, wpt, rb, b_proj, y);
}

// Round 2
// 428.310 us; speedup vs baseline: 1.4640x; 1.4640x over previous
//
#include <hip/hip_runtime.h>

typedef __attribute__((ext_vector_type(8))) short bf16x8;
typedef __attribute__((ext_vector_type(4))) float f32x4;

#define MFMA(a, b, c) __builtin_amdgcn_mfma_f32_16x16x32_bf16(a, b, c, 0, 0, 0)

__device__ __forceinline__ unsigned int pack2(float x, float y) {
  union { float f; unsigned u; } a{x}, b{y};
  unsigned ax = a.u + 0x7FFFu + ((a.u >> 16) & 1u);
  unsigned bx = b.u + 0x7FFFu + ((b.u >> 16) & 1u);
  return (ax >> 16) | (bx & 0xFFFF0000u);
}
__device__ __forceinline__ unsigned short f2bf(float x) {
  union { float f; unsigned u; } a{x};
  unsigned r = a.u + 0x7FFFu + ((a.u >> 16) & 1u);
  return (unsigned short)(r >> 16);
}

// token t (shifted-window order) -> flat pixel base offset (elements) in x / y
__device__ __forceinline__ int src_off(int t) {
  int wi = t >> 6, n = t & 63;
  int b = wi >> 10, wr = (wi >> 5) & 31, wc = wi & 31;
  int hh = (wr * 8 + (n >> 3) + 4) & 255;
  int ww = (wc * 8 + (n & 7) + 4) & 255;
  return ((((b << 8) | hh) << 8) | ww) << 8;
}

// ---- prep: weight transposes (bf16) + fragment-ordered relative bias ------
__global__ __launch_bounds__(256) void prep_kernel(
    const float* __restrict__ w_qkv, const float* __restrict__ w_proj,
    const float* __restrict__ bias_table,
    unsigned short* __restrict__ wqkvt, unsigned short* __restrict__ wpt,
    float* __restrict__ rb2) {
  int i = blockIdx.x * 256 + threadIdx.x;
  if (i < 196608) {                        // wqkvt[n][k] = w_qkv[k][n]
    wqkvt[i] = f2bf(w_qkv[(i & 255) * 768 + (i >> 8)]);
  } else if (i < 262144) {                 // wpt[n][k] = w_proj[k][n]
    int j = i - 196608;
    wpt[j] = f2bf(w_proj[(j & 255) * 256 + (j >> 8)]);
  } else {                                 // rb2[h][mt][nt][g][ln][jr]
    int j = i - 262144;
    int jr = j & 3, ln = (j >> 2) & 15, g = (j >> 6) & 3;
    int nt = (j >> 8) & 3, mt = (j >> 10) & 3, h = j >> 12;
    int row = 16 * mt + 4 * g + jr;        // query token n
    int col = 16 * nt + ln;                // key token m
    int idx = ((row >> 3) - (col >> 3) + 7) * 15 + ((row & 7) - (col & 7) + 7);
    rb2[j] = bias_table[idx * 8 + h];
  }
}

// ---- fused: stage x -> QKV GEMM -> attention -> proj, 1 block per window --
__global__ __launch_bounds__(512, 2) void fused_kernel(
    const float* __restrict__ x, const unsigned short* __restrict__ wqkvt,
    const float* __restrict__ b_qkv, const unsigned short* __restrict__ wpt,
    const float* __restrict__ b_proj, const float* __restrict__ rb2,
    float* __restrict__ y) {
  // LDS map (ushort elems): XL [64][256] swizzled at 0 (16384)
  // per-wave region at 16384 + h*7424: Qh 64x40 | Kh 64x40 (later P-scratch) | VT 32x72
  __shared__ unsigned short sm[75776];     // 148 KiB -> 1 block/CU
  int wi = blockIdx.x;
  int tid = threadIdx.x;
  int h = tid >> 6, lane = tid & 63, ln = lane & 15, g = lane >> 4;

  // -------- phase 0: stage window x -> XL bf16 (swizzled) --------
  int tb = wi * 64;
#pragma unroll
  for (int r = 0; r < 2; ++r) {
    int u = tid + 512 * r;
    int tok = u >> 4, ck = u & 15;         // 16-float chunk of one token row
    const float4* s4 = (const float4*)(x + src_off(tb + tok) + ck * 16);
    float4 f0 = s4[0], f1 = s4[1], f2 = s4[2], f3 = s4[3];
    uint4 w0, w1;
    w0.x = pack2(f0.x, f0.y); w0.y = pack2(f0.z, f0.w);
    w0.z = pack2(f1.x, f1.y); w0.w = pack2(f1.z, f1.w);
    w1.x = pack2(f2.x, f2.y); w1.y = pack2(f2.z, f2.w);
    w1.z = pack2(f3.x, f3.y); w1.w = pack2(f3.z, f3.w);
    int base = tok * 512 + ck * 32, swz = (tok & 7) << 4;
    *(uint4*)((char*)sm + ((base) ^ swz)) = w0;
    *(uint4*)((char*)sm + ((base + 16) ^ swz)) = w1;
  }
  __syncthreads();

  // -------- phase 1: QKV GEMM, wave h owns head h's Q/K/V columns --------
  f32x4 aq[4][2] = {}, ak[4][2] = {}, av[4][2] = {};
#pragma unroll
  for (int ks = 0; ks < 8; ++ks) {
    bf16x8 af[4];
#pragma unroll
    for (int mt = 0; mt < 4; ++mt) {
      int row = 16 * mt + ln;
      af[mt] = *(const bf16x8*)((char*)sm + ((row * 512 + ks * 64 + 16 * g) ^ ((row & 7) << 4)));
    }
    bf16x8 bq[2], bk[2], bv[2];
#pragma unroll
    for (int nt = 0; nt < 2; ++nt) {
      int nr = 32 * h + 16 * nt + ln;
      bq[nt] = *(const bf16x8*)(wqkvt + nr * 256 + ks * 32 + 8 * g);
      bk[nt] = *(const bf16x8*)(wqkvt + (256 + nr) * 256 + ks * 32 + 8 * g);
      bv[nt] = *(const bf16x8*)(wqkvt + (512 + nr) * 256 + ks * 32 + 8 * g);
    }
#pragma unroll
    for (int mt = 0; mt < 4; ++mt)
#pragma unroll
      for (int nt = 0; nt < 2; ++nt) {
        aq[mt][nt] = MFMA(af[mt], bq[nt], aq[mt][nt]);
        ak[mt][nt] = MFMA(af[mt], bk[nt], ak[mt][nt]);
        av[mt][nt] = MFMA(af[mt], bv[nt], av[mt][nt]);
      }
  }
  unsigned short* Qh = sm + 16384 + h * 7424;
  unsigned short* Kh = Qh + 2560;
  unsigned short* VT = Qh + 5120;
#pragma unroll
  for (int nt = 0; nt < 2; ++nt) {
    float bq_ = b_qkv[32 * h + 16 * nt + ln];
    float bk_ = b_qkv[256 + 32 * h + 16 * nt + ln];
    float bv_ = b_qkv[512 + 32 * h + 16 * nt + ln];
#pragma unroll
    for (int mt = 0; mt < 4; ++mt) {
      ushort4 vp;                          // V^T: 4 consecutive tokens, 8B write
      vp.x = f2bf(av[mt][nt][0] + bv_); vp.y = f2bf(av[mt][nt][1] + bv_);
      vp.z = f2bf(av[mt][nt][2] + bv_); vp.w = f2bf(av[mt][nt][3] + bv_);
      *(ushort4*)&VT[(16 * nt + ln) * 72 + 16 * mt + 4 * g] = vp;
#pragma unroll
      for (int jr = 0; jr < 4; ++jr) {
        int tok = 16 * mt + 4 * g + jr;
        Qh[tok * 40 + 16 * nt + ln] = f2bf((aq[mt][nt][jr] + bq_) * 0.17677669529663687f);
        Kh[tok * 40 + 16 * nt + ln] = f2bf(ak[mt][nt][jr] + bk_);
      }
    }
  }

  // -------- phase 2: attention (wave-local, no barrier needed) --------
  bf16x8 qf[4], kf[4];
#pragma unroll
  for (int mt = 0; mt < 4; ++mt) qf[mt] = *(const bf16x8*)&Qh[(16 * mt + ln) * 40 + 8 * g];
#pragma unroll
  for (int nt = 0; nt < 4; ++nt) kf[nt] = *(const bf16x8*)&Kh[(16 * nt + ln) * 40 + 8 * g];

  f32x4 s[4][4];
  const float* rbw = rb2 + h * 4096;
#pragma unroll
  for (int mt = 0; mt < 4; ++mt)
#pragma unroll
    for (int nt = 0; nt < 4; ++nt)
      s[mt][nt] = *(const f32x4*)(rbw + ((((mt * 4 + nt) * 4 + g) * 16 + ln) * 4));
#pragma unroll
  for (int mt = 0; mt < 4; ++mt)
#pragma unroll
    for (int nt = 0; nt < 4; ++nt)
      s[mt][nt] = MFMA(qf[mt], kf[nt], s[mt][nt]);

#pragma unroll
  for (int mt = 0; mt < 4; ++mt) {
#pragma unroll
    for (int jr = 0; jr < 4; ++jr) {
      float mx = fmaxf(fmaxf(s[mt][0][jr], s[mt][1][jr]), fmaxf(s[mt][2][jr], s[mt][3][jr]));
      mx = fmaxf(mx, __shfl_xor(mx, 1));
      mx = fmaxf(mx, __shfl_xor(mx, 2));
      mx = fmaxf(mx, __shfl_xor(mx, 4));
      mx = fmaxf(mx, __shfl_xor(mx, 8));
      float sum = 0.f;
#pragma unroll
      for (int nt = 0; nt < 4; ++nt) {
        float p = __expf(s[mt][nt][jr] - mx);
        s[mt][nt][jr] = p; sum += p;
      }
      sum += __shfl_xor(sum, 1);
      sum += __shfl_xor(sum, 2);
      sum += __shfl_xor(sum, 4);
      sum += __shfl_xor(sum, 8);
      float inv = 1.f / sum;
#pragma unroll
      for (int nt = 0; nt < 4; ++nt) s[mt][nt][jr] *= inv;
    }
  }

  // PV: P chunks through Kh-region scratch (pitch 40), V^T frags from VT
  unsigned short* sc = Kh;
  f32x4 o[4][2] = {};
#pragma unroll
  for (int kk = 0; kk < 2; ++kk) {
#pragma unroll
    for (int mt = 0; mt < 4; ++mt)
#pragma unroll
      for (int q = 0; q < 2; ++q)
#pragma unroll
        for (int jr = 0; jr < 4; ++jr)
          sc[(16 * mt + 4 * g + jr) * 40 + q * 16 + ln] = f2bf(s[mt][2 * kk + q][jr]);
    bf16x8 vf[2];
#pragma unroll
    for (int nd = 0; nd < 2; ++nd)
      vf[nd] = *(const bf16x8*)&VT[(16 * nd + ln) * 72 + 32 * kk + 8 * g];
#pragma unroll
    for (int mt = 0; mt < 4; ++mt) {
      bf16x8 pa = *(const bf16x8*)&sc[(16 * mt + ln) * 40 + 8 * g];
      o[mt][0] = MFMA(pa, vf[0], o[mt][0]);
      o[mt][1] = MFMA(pa, vf[1], o[mt][1]);
    }
  }
  // attention-out into own Qh region (Q frags already consumed)
#pragma unroll
  for (int mt = 0; mt < 4; ++mt)
#pragma unroll
    for (int nd = 0; nd < 2; ++nd)
#pragma unroll
      for (int jr = 0; jr < 4; ++jr)
        Qh[(16 * mt + 4 * g + jr) * 40 + 16 * nd + ln] = f2bf(o[mt][nd][jr]);
  __syncthreads();

  // -------- phase 3: proj; K-step ks = head ks's AO region --------
  f32x4 a2[4][2] = {};
#pragma unroll
  for (int ks = 0; ks < 8; ++ks) {
    const unsigned short* AO = sm + 16384 + ks * 7424;
    bf16x8 af2[4], bf2[2];
#pragma unroll
    for (int mt = 0; mt < 4; ++mt)
      af2[mt] = *(const bf16x8*)&AO[(16 * mt + ln) * 40 + 8 * g];
#pragma unroll
    for (int nt = 0; nt < 2; ++nt)
      bf2[nt] = *(const bf16x8*)(wpt + (32 * h + 16 * nt + ln) * 256 + ks * 32 + 8 * g);
#pragma unroll
    for (int mt = 0; mt < 4; ++mt) {
      a2[mt][0] = MFMA(af2[mt], bf2[0], a2[mt][0]);
      a2[mt][1] = MFMA(af2[mt], bf2[1], a2[mt][1]);
    }
  }
  // epilogue: un-shift scatter + proj bias
  int b = wi >> 10, wr = (wi >> 5) & 31, wc = wi & 31;
#pragma unroll
  for (int mt = 0; mt < 4; ++mt)
#pragma unroll
    for (int jr = 0; jr < 4; ++jr) {
      int n = 16 * mt + 4 * g + jr;
      int hh = (wr * 8 + (n >> 3) + 4) & 255;
      int ww = (wc * 8 + (n & 7) + 4) & 255;
      int off = ((((b << 8) | hh) << 8) | ww) << 8;
#pragma unroll
      for (int nt = 0; nt < 2; ++nt) {
        int col = 32 * h + 16 * nt + ln;
        y[off + col] = a2[mt][nt][jr] + b_proj[col];
      }
    }
}

extern "C" void kernel_launch(void* const* d_in, const int* in_sizes, int n_in,
                              void* d_out, int out_size, void* d_ws, size_t ws_size,
                              hipStream_t stream) {
  const float* x          = (const float*)d_in[0];
  const float* w_qkv      = (const float*)d_in[1];
  const float* b_qkv      = (const float*)d_in[2];
  const float* w_proj     = (const float*)d_in[3];
  const float* b_proj     = (const float*)d_in[4];
  const float* bias_table = (const float*)d_in[5];
  char* ws = (char*)d_ws;
  // ws layout: wqkvt 384 KiB | wpt 128 KiB | rb2 128 KiB
  unsigned short* wqkvt = (unsigned short*)(ws);
  unsigned short* wpt   = (unsigned short*)(ws + 393216);
  float* rb2            = (float*)(ws + 524288);
  float* y = (float*)d_out;

  prep_kernel<<<1152, 256, 0, stream>>>(w_qkv, w_proj, bias_table, wqkvt, wpt, rb2);
  fused_kernel<<<4096, 512, 0, stream>>>(x, wqkvt, b_qkv, wpt, b_proj, rb2, y);
}

// Round 3
// 369.552 us; speedup vs baseline: 1.6967x; 1.1590x over previous
//
#include <hip/hip_runtime.h>

typedef __attribute__((ext_vector_type(8))) short bf16x8;
typedef __attribute__((ext_vector_type(4))) float f32x4;

#define MFMA(a, b, c) __builtin_amdgcn_mfma_f32_16x16x32_bf16(a, b, c, 0, 0, 0)

__device__ __forceinline__ unsigned int pack2(float x, float y) {
  union { float f; unsigned u; } a{x}, b{y};
  unsigned ax = a.u + 0x7FFFu + ((a.u >> 16) & 1u);
  unsigned bx = b.u + 0x7FFFu + ((b.u >> 16) & 1u);
  return (ax >> 16) | (bx & 0xFFFF0000u);
}
__device__ __forceinline__ unsigned short f2bf(float x) {
  union { float f; unsigned u; } a{x};
  unsigned r = a.u + 0x7FFFu + ((a.u >> 16) & 1u);
  return (unsigned short)(r >> 16);
}

// token t (shifted-window order) -> flat pixel base offset (elements) in x / y
__device__ __forceinline__ int src_off(int t) {
  int wi = t >> 6, n = t & 63;
  int b = wi >> 10, wr = (wi >> 5) & 31, wc = wi & 31;
  int hh = (wr * 8 + (n >> 3) + 4) & 255;
  int ww = (wc * 8 + (n & 7) + 4) & 255;
  return ((((b << 8) | hh) << 8) | ww) << 8;
}

// ---- prep: weight transposes (bf16) + fragment-ordered relative bias ------
__global__ __launch_bounds__(256) void prep_kernel(
    const float* __restrict__ w_qkv, const float* __restrict__ w_proj,
    const float* __restrict__ bias_table,
    unsigned short* __restrict__ wqkvt, unsigned short* __restrict__ wpt,
    float* __restrict__ rb2) {
  int i = blockIdx.x * 256 + threadIdx.x;
  if (i < 196608) {                        // wqkvt[n][k] = w_qkv[k][n]
    wqkvt[i] = f2bf(w_qkv[(i & 255) * 768 + (i >> 8)]);
  } else if (i < 262144) {                 // wpt[n][k] = w_proj[k][n]
    int j = i - 196608;
    wpt[j] = f2bf(w_proj[(j & 255) * 256 + (j >> 8)]);
  } else {                                 // rb2[h][mt][nt][g][ln][jr]
    int j = i - 262144;
    int jr = j & 3, ln = (j >> 2) & 15, g = (j >> 6) & 3;
    int nt = (j >> 8) & 3, mt = (j >> 10) & 3, h = j >> 12;
    int row = 16 * mt + 4 * g + jr;        // query token n
    int col = 16 * nt + ln;                // key token m
    int idx = ((row >> 3) - (col >> 3) + 7) * 15 + ((row & 7) - (col & 7) + 7);
    rb2[j] = bias_table[idx * 8 + h];
  }
}

// ---- fused: stage x -> QKV -> attention -> proj; 72 KiB LDS, 2 blocks/CU --
__global__ __launch_bounds__(512, 4) void fused_kernel(
    const float* __restrict__ x, const unsigned short* __restrict__ wqkvt,
    const float* __restrict__ b_qkv, const unsigned short* __restrict__ wpt,
    const float* __restrict__ b_proj, const float* __restrict__ rb2,
    float* __restrict__ y) {
  // LDS (ushort elems): XL [64][256] swizzled at 0 (16384 elems = 32 KiB)
  // per-wave R1 at 16384 + h*2560 (5 KiB), serially reused:
  //   Q(p40) -> K(p40) -> VT(32x72) -> P(p40) -> AO(p40)
  __shared__ unsigned short sm[36864];     // 72 KiB
  int wi = blockIdx.x;
  int tid = threadIdx.x;
  int h = tid >> 6, lane = tid & 63, ln = lane & 15, g = lane >> 4;

  // -------- phase 0: stage window x -> XL bf16 (swizzled) --------
  int tb = wi * 64;
#pragma unroll
  for (int r = 0; r < 2; ++r) {
    int u = tid + 512 * r;
    int tok = u >> 4, ck = u & 15;
    const float4* s4 = (const float4*)(x + src_off(tb + tok) + ck * 16);
    float4 f0 = s4[0], f1 = s4[1], f2 = s4[2], f3 = s4[3];
    uint4 w0, w1;
    w0.x = pack2(f0.x, f0.y); w0.y = pack2(f0.z, f0.w);
    w0.z = pack2(f1.x, f1.y); w0.w = pack2(f1.z, f1.w);
    w1.x = pack2(f2.x, f2.y); w1.y = pack2(f2.z, f2.w);
    w1.z = pack2(f3.x, f3.y); w1.w = pack2(f3.z, f3.w);
    int base = tok * 512 + ck * 32, swz = (tok & 7) << 4;
    *(uint4*)((char*)sm + ((base) ^ swz)) = w0;
    *(uint4*)((char*)sm + ((base + 16) ^ swz)) = w1;
  }
  __syncthreads();

  unsigned short* R1 = sm + 16384 + h * 2560;

  // -------- pass A: Q and K for head h --------
  f32x4 aq[4][2] = {}, ak[4][2] = {};
#pragma unroll
  for (int ks = 0; ks < 8; ++ks) {
    bf16x8 af[4];
#pragma unroll
    for (int mt = 0; mt < 4; ++mt) {
      int row = 16 * mt + ln;
      af[mt] = *(const bf16x8*)((char*)sm + ((row * 512 + ks * 64 + 16 * g) ^ ((row & 7) << 4)));
    }
    bf16x8 bq[2], bk[2];
#pragma unroll
    for (int nt = 0; nt < 2; ++nt) {
      int nr = 32 * h + 16 * nt + ln;
      bq[nt] = *(const bf16x8*)(wqkvt + nr * 256 + ks * 32 + 8 * g);
      bk[nt] = *(const bf16x8*)(wqkvt + (256 + nr) * 256 + ks * 32 + 8 * g);
    }
#pragma unroll
    for (int mt = 0; mt < 4; ++mt)
#pragma unroll
      for (int nt = 0; nt < 2; ++nt) {
        aq[mt][nt] = MFMA(af[mt], bq[nt], aq[mt][nt]);
        ak[mt][nt] = MFMA(af[mt], bk[nt], ak[mt][nt]);
      }
  }
  // Q -> R1 (pitch 40), extract qf
#pragma unroll
  for (int nt = 0; nt < 2; ++nt) {
    float bq_ = b_qkv[32 * h + 16 * nt + ln];
#pragma unroll
    for (int mt = 0; mt < 4; ++mt)
#pragma unroll
      for (int jr = 0; jr < 4; ++jr)
        R1[(16 * mt + 4 * g + jr) * 40 + 16 * nt + ln] =
            f2bf((aq[mt][nt][jr] + bq_) * 0.17677669529663687f);
  }
  bf16x8 qf[4];
#pragma unroll
  for (int mt = 0; mt < 4; ++mt) qf[mt] = *(const bf16x8*)&R1[(16 * mt + ln) * 40 + 8 * g];
  // K -> R1 (overwrite), extract kf
#pragma unroll
  for (int nt = 0; nt < 2; ++nt) {
    float bk_ = b_qkv[256 + 32 * h + 16 * nt + ln];
#pragma unroll
    for (int mt = 0; mt < 4; ++mt)
#pragma unroll
      for (int jr = 0; jr < 4; ++jr)
        R1[(16 * mt + 4 * g + jr) * 40 + 16 * nt + ln] = f2bf(ak[mt][nt][jr] + bk_);
  }
  bf16x8 kf[4];
#pragma unroll
  for (int nt = 0; nt < 4; ++nt) kf[nt] = *(const bf16x8*)&R1[(16 * nt + ln) * 40 + 8 * g];

  // -------- pass B: V for head h (af re-read from XL) --------
  f32x4 av[4][2] = {};
#pragma unroll
  for (int ks = 0; ks < 8; ++ks) {
    bf16x8 af[4];
#pragma unroll
    for (int mt = 0; mt < 4; ++mt) {
      int row = 16 * mt + ln;
      af[mt] = *(const bf16x8*)((char*)sm + ((row * 512 + ks * 64 + 16 * g) ^ ((row & 7) << 4)));
    }
    bf16x8 bv[2];
#pragma unroll
    for (int nt = 0; nt < 2; ++nt) {
      int nr = 512 + 32 * h + 16 * nt + ln;
      bv[nt] = *(const bf16x8*)(wqkvt + nr * 256 + ks * 32 + 8 * g);
    }
#pragma unroll
    for (int mt = 0; mt < 4; ++mt)
#pragma unroll
      for (int nt = 0; nt < 2; ++nt)
        av[mt][nt] = MFMA(af[mt], bv[nt], av[mt][nt]);
  }
  // V^T -> R1 (32x72, overwrite), extract vf[kk][nd]
#pragma unroll
  for (int nt = 0; nt < 2; ++nt) {
    float bv_ = b_qkv[512 + 32 * h + 16 * nt + ln];
#pragma unroll
    for (int mt = 0; mt < 4; ++mt) {
      ushort4 vp;
      vp.x = f2bf(av[mt][nt][0] + bv_); vp.y = f2bf(av[mt][nt][1] + bv_);
      vp.z = f2bf(av[mt][nt][2] + bv_); vp.w = f2bf(av[mt][nt][3] + bv_);
      *(ushort4*)&R1[(16 * nt + ln) * 72 + 16 * mt + 4 * g] = vp;
    }
  }
  bf16x8 vf[2][2];
#pragma unroll
  for (int kk = 0; kk < 2; ++kk)
#pragma unroll
    for (int nd = 0; nd < 2; ++nd)
      vf[kk][nd] = *(const bf16x8*)&R1[(16 * nd + ln) * 72 + 32 * kk + 8 * g];

  // -------- QK^T (bias preloaded) --------
  f32x4 s[4][4];
  const float* rbw = rb2 + h * 4096;
#pragma unroll
  for (int mt = 0; mt < 4; ++mt)
#pragma unroll
    for (int nt = 0; nt < 4; ++nt)
      s[mt][nt] = *(const f32x4*)(rbw + ((((mt * 4 + nt) * 4 + g) * 16 + ln) * 4));
#pragma unroll
  for (int mt = 0; mt < 4; ++mt)
#pragma unroll
    for (int nt = 0; nt < 4; ++nt)
      s[mt][nt] = MFMA(qf[mt], kf[nt], s[mt][nt]);

  // -------- softmax (wave-parallel, rows in 16-lane groups) --------
#pragma unroll
  for (int mt = 0; mt < 4; ++mt) {
#pragma unroll
    for (int jr = 0; jr < 4; ++jr) {
      float mx = fmaxf(fmaxf(s[mt][0][jr], s[mt][1][jr]), fmaxf(s[mt][2][jr], s[mt][3][jr]));
      mx = fmaxf(mx, __shfl_xor(mx, 1));
      mx = fmaxf(mx, __shfl_xor(mx, 2));
      mx = fmaxf(mx, __shfl_xor(mx, 4));
      mx = fmaxf(mx, __shfl_xor(mx, 8));
      float sum = 0.f;
#pragma unroll
      for (int nt = 0; nt < 4; ++nt) {
        float p = __expf(s[mt][nt][jr] - mx);
        s[mt][nt][jr] = p; sum += p;
      }
      sum += __shfl_xor(sum, 1);
      sum += __shfl_xor(sum, 2);
      sum += __shfl_xor(sum, 4);
      sum += __shfl_xor(sum, 8);
      float inv = 1.f / sum;
#pragma unroll
      for (int nt = 0; nt < 4; ++nt) s[mt][nt][jr] *= inv;
    }
  }

  // -------- PV: P through R1 (pitch 40, overwrites VT after vf read) --------
  f32x4 o[4][2] = {};
#pragma unroll
  for (int kk = 0; kk < 2; ++kk) {
#pragma unroll
    for (int mt = 0; mt < 4; ++mt)
#pragma unroll
      for (int q = 0; q < 2; ++q)
#pragma unroll
        for (int jr = 0; jr < 4; ++jr)
          R1[(16 * mt + 4 * g + jr) * 40 + q * 16 + ln] = f2bf(s[mt][2 * kk + q][jr]);
#pragma unroll
    for (int mt = 0; mt < 4; ++mt) {
      bf16x8 pa = *(const bf16x8*)&R1[(16 * mt + ln) * 40 + 8 * g];
      o[mt][0] = MFMA(pa, vf[kk][0], o[mt][0]);
      o[mt][1] = MFMA(pa, vf[kk][1], o[mt][1]);
    }
  }
  // attention-out -> R1 (pitch 40)
#pragma unroll
  for (int mt = 0; mt < 4; ++mt)
#pragma unroll
    for (int nd = 0; nd < 2; ++nd)
#pragma unroll
      for (int jr = 0; jr < 4; ++jr)
        R1[(16 * mt + 4 * g + jr) * 40 + 16 * nd + ln] = f2bf(o[mt][nd][jr]);
  __syncthreads();

  // -------- proj: K-step ks = head ks's AO region --------
  f32x4 a2[4][2] = {};
#pragma unroll
  for (int ks = 0; ks < 8; ++ks) {
    const unsigned short* AO = sm + 16384 + ks * 2560;
    bf16x8 af2[4], bf2[2];
#pragma unroll
    for (int mt = 0; mt < 4; ++mt)
      af2[mt] = *(const bf16x8*)&AO[(16 * mt + ln) * 40 + 8 * g];
#pragma unroll
    for (int nt = 0; nt < 2; ++nt)
      bf2[nt] = *(const bf16x8*)(wpt + (32 * h + 16 * nt + ln) * 256 + ks * 32 + 8 * g);
#pragma unroll
    for (int mt = 0; mt < 4; ++mt) {
      a2[mt][0] = MFMA(af2[mt], bf2[0], a2[mt][0]);
      a2[mt][1] = MFMA(af2[mt], bf2[1], a2[mt][1]);
    }
  }
  // epilogue: un-shift scatter + proj bias
  int b = wi >> 10, wr = (wi >> 5) & 31, wc = wi & 31;
#pragma unroll
  for (int mt = 0; mt < 4; ++mt)
#pragma unroll
    for (int jr = 0; jr < 4; ++jr) {
      int n = 16 * mt + 4 * g + jr;
      int hh = (wr * 8 + (n >> 3) + 4) & 255;
      int ww = (wc * 8 + (n & 7) + 4) & 255;
      int off = ((((b << 8) | hh) << 8) | ww) << 8;
#pragma unroll
      for (int nt = 0; nt < 2; ++nt) {
        int col = 32 * h + 16 * nt + ln;
        y[off + col] = a2[mt][nt][jr] + b_proj[col];
      }
    }
}

extern "C" void kernel_launch(void* const* d_in, const int* in_sizes, int n_in,
                              void* d_out, int out_size, void* d_ws, size_t ws_size,
                              hipStream_t stream) {
  const float* x          = (const float*)d_in[0];
  const float* w_qkv      = (const float*)d_in[1];
  const float* b_qkv      = (const float*)d_in[2];
  const float* w_proj     = (const float*)d_in[3];
  const float* b_proj     = (const float*)d_in[4];
  const float* bias_table = (const float*)d_in[5];
  char* ws = (char*)d_ws;
  // ws layout: wqkvt 384 KiB | wpt 128 KiB | rb2 128 KiB
  unsigned short* wqkvt = (unsigned short*)(ws);
  unsigned short* wpt   = (unsigned short*)(ws + 393216);
  float* rb2            = (float*)(ws + 524288);
  float* y = (float*)d_out;

  prep_kernel<<<1152, 256, 0, stream>>>(w_qkv, w_proj, bias_table, wqkvt, wpt, rb2);
  fused_kernel<<<4096, 512, 0, stream>>>(x, wqkvt, b_qkv, wpt, b_proj, rb2, y);
}